// Round 30
// baseline (56.884 us; speedup 1.0000x reference)
//
#include <hip/hip_runtime.h>

#define MODES 10
#define NPH 5
#define DEPTH 10
#define NST5 2002
#define KPAD 2016
#define BATCH 4096
#define KSPLIT 8

typedef __attribute__((ext_vector_type(8))) short bf16x8;
typedef __attribute__((ext_vector_type(4))) float f32x4;

// ============ COMPILE-TIME transition tables ============
// Levels 0-3: degree-bucketed compact CSR (divergence-free level steps).
// Level 4: t-ordered, UNIFORM 5 edges/target (padded with zero-amp slot 715).
struct DevTables {
    unsigned meta[1000];       // levels 0-3 only
    unsigned edges[2860 + NST5 * 5];
    float c2[NST5];
};

constexpr DevTables build_tables() {
    DevTables T{};
    const int sizes[6] = {1, 10, 55, 220, 715, 2002};
    const int mb[5] = {0, 10, 65, 285, 1000};
    const int eb[5] = {0, 10, 110, 660, 2860};
    const float fact[6] = {1.f, 1.f, 2.f, 6.f, 24.f, 120.f};

    unsigned prev[715] = {};
    unsigned cur[2002] = {};
    int dd[2002] = {};
    int s[10] = {};
    int prevN = 1;
    prev[0] = 0u;

    for (int lvl = 1; lvl <= 5; ++lvl) {
        const int k = lvl - 1;
        const int N = sizes[lvl];
        int cnt[5] = {0, 0, 0, 0, 0};
        for (int p = 0; p < 10; ++p) s[p] = 0;
        s[0] = lvl;
        for (int t = 0; t < N; ++t) {
            unsigned P = 0;
            int d = 0;
            for (int p = 0; p < 10; ++p) {
                P |= (unsigned)s[p] << (3 * (9 - p));
                d += (s[p] > 0) ? 1 : 0;
            }
            cur[t] = P;
            dd[t] = d;
            cnt[d - 1] += 1;
            int p = 8;
            while (p >= 0 && s[p] == 0) --p;
            if (p >= 0) {
                int rest = 1;
                for (int q = p + 1; q < 10; ++q) { rest += s[q]; s[q] = 0; }
                s[p] -= 1;
                s[p + 1] = rest;
            }
        }
        int bp[5] = {}, be[5] = {};
        {
            int pp = 0, ee = 0;
            for (int d = 0; d < 5; ++d) {
                bp[d] = pp; be[d] = ee;
                pp += cnt[d]; ee += cnt[d] * (d + 1);
            }
        }
        for (int p = 0; p < 10; ++p) s[p] = 0;
        s[0] = lvl;
        for (int t = 0; t < N; ++t) {
            const int d = dd[t];
            int pos = 0, eo = 0;
            if (lvl == 5) {                 // uniform: 5 slots at t*5
                pos = -1;
                eo = t * 5;
            } else {                        // bucketed
                pos = mb[k] + bp[d - 1];
                eo = be[d - 1];
                bp[d - 1] += 1;
                be[d - 1] += d;
                T.meta[pos] = (unsigned)t | ((unsigned)d << 11) | ((unsigned)eo << 14);
            }
            int w = 0;
            for (int j = 0; j < 10; ++j) {
                if (s[j] > 0) {
                    unsigned pp2 = cur[t] - (1u << (3 * (9 - j)));
                    int lo = 0, hi = prevN - 1;
                    while (lo < hi) {
                        int mid = (lo + hi) >> 1;
                        if (prev[mid] > pp2) lo = mid + 1; else hi = mid;
                    }
                    T.edges[eb[k] + eo + w] = (unsigned)lo | ((unsigned)j << 12);
                    w += 1;
                }
            }
            if (lvl == 5) {
                for (; w < 5; ++w) T.edges[eb[k] + eo + w] = 715u;  // zero amp
                float c2 = 1.f;
                for (int j = 0; j < 10; ++j) c2 *= fact[s[j]];
                T.c2[t] = c2;
            }
            int p = 8;
            while (p >= 0 && s[p] == 0) --p;
            if (p >= 0) {
                int rest = 1;
                for (int q = p + 1; q < 10; ++q) { rest += s[q]; s[q] = 0; }
                s[p] -= 1;
                s[p + 1] = rest;
            }
        }
        if (lvl < 5) {
            for (int t = 0; t < N; ++t) prev[t] = cur[t];
            prevN = N;
        }
    }
    return T;
}

__device__ const DevTables g_T = build_tables();

// ---------- runtime scratch ----------
__device__ __align__(16) unsigned g_pack[(size_t)BATCH * KPAD];
__device__ __align__(16) unsigned short g_WhiT[64 * KPAD];   // [col][k]
__device__ __align__(16) unsigned short g_WloT[64 * KPAD];
__device__ float2 g_M[MODES][NPH];
__device__ float g_part[(size_t)KSPLIT * BATCH * 64];

__device__ __forceinline__ unsigned short f2bf(float f) {
    unsigned u = __float_as_uint(f);
    unsigned r = (u + 0x7FFF + ((u >> 16) & 1)) >> 16;   // RNE
    return (unsigned short)r;
}
__device__ __forceinline__ float bf2f(unsigned short h) {
    return __uint_as_float((unsigned)h << 16);
}

// ---------- prep: blocks 0..503 split W; block 504 builds g_M ----------
__global__ __launch_bounds__(256)
void k_prep(const float* __restrict__ theta, const float* __restrict__ W) {
    const int tid = threadIdx.x;
    if (blockIdx.x == 504) {
        __shared__ float2 Ush[MODES][NPH];
        const int r = tid / 5, c = tid % 5;
        const bool act = (tid < 50);
        float2 val = make_float2((act && r == c) ? 1.f : 0.f, 0.f);
        for (int l = 0; l < DEPTH; l++) {
            if (act && l > 0) {
                float ang = theta[(l - 1) * MODES + r];
                float s_, c_; sincosf(ang, &s_, &c_);
                float nx = val.x * c_ - val.y * s_;
                float ny = val.x * s_ + val.y * c_;
                val = make_float2(nx, ny);
            }
            if (act) Ush[r][c] = val;
            __syncthreads();
            float2 nv = val;
            if (act) {
                int o = l & 1;
                int lo = r - o;
                int partner = o + (lo ^ 1);
                if (lo >= 0 && partner < MODES) {
                    float2 pb = Ush[partner][c];
                    const float inv = 0.70710678118654752f;
                    nv.x = inv * (val.x - pb.y);
                    nv.y = inv * (val.y + pb.x);
                }
            }
            __syncthreads();
            val = nv;
        }
        if (act) g_M[r][c] = val;
        return;
    }
    int id = blockIdx.x * 256 + tid;       // 504*256 = 129024 = 64*2016
    int k = id / 64, c = id % 64;
    float w = (k < NST5) ? W[(size_t)k * 64 + c] : 0.f;
    unsigned short hi = f2bf(w);
    unsigned short lo = f2bf(w - bf2f(hi));
    g_WhiT[(size_t)c * KPAD + k] = hi;
    g_WloT[(size_t)c * KPAD + k] = lo;
}

// ---------- SLOS level step, compact edges, 4 batch elems packed ----------
__device__ __forceinline__ void slos_lvl(const float4 (*__restrict__ src)[2],
                                         float4 (*__restrict__ dst)[2],
                                         const unsigned* __restrict__ meta,
                                         const unsigned* __restrict__ edges,
                                         int N, int tid,
                                         const float4 (*Ua)[NPH],
                                         const float4 (*Ub)[NPH], int k) {
    for (int pos = tid; pos < N; pos += 256) {
        unsigned m = meta[pos];
        int t = m & 0x7FF;
        int d = (m >> 11) & 0x7;
        const unsigned* ee = edges + (m >> 14);
        float ax0 = 0.f, ay0 = 0.f, ax1 = 0.f, ay1 = 0.f;
        float ax2 = 0.f, ay2 = 0.f, ax3 = 0.f, ay3 = 0.f;
        for (int sl = 0; sl < d; sl++) {
            unsigned e = ee[sl];
            int idx = e & 0xFFF;
            int j = (e >> 12) & 0xF;
            float4 a01 = src[idx][0];
            float4 a23 = src[idx][1];
            float4 u01 = Ua[j][k];
            float4 u23 = Ub[j][k];
            ax0 = fmaf(u01.x, a01.x, ax0); ax0 = fmaf(-u01.y, a01.y, ax0);
            ay0 = fmaf(u01.x, a01.y, ay0); ay0 = fmaf( u01.y, a01.x, ay0);
            ax1 = fmaf(u01.z, a01.z, ax1); ax1 = fmaf(-u01.w, a01.w, ax1);
            ay1 = fmaf(u01.z, a01.w, ay1); ay1 = fmaf( u01.w, a01.z, ay1);
            ax2 = fmaf(u23.x, a23.x, ax2); ax2 = fmaf(-u23.y, a23.y, ax2);
            ay2 = fmaf(u23.x, a23.y, ay2); ay2 = fmaf( u23.y, a23.x, ay2);
            ax3 = fmaf(u23.z, a23.z, ax3); ax3 = fmaf(-u23.w, a23.w, ax3);
            ay3 = fmaf(u23.z, a23.w, ay3); ay3 = fmaf( u23.w, a23.z, ay3);
        }
        dst[t][0] = make_float4(ax0, ay0, ax1, ay1);
        dst[t][1] = make_float4(ax2, ay2, ax3, ay3);
    }
    __syncthreads();
}

// ---------- SLOS, 4 batch elements per block; packed u32 hi|lo out ----------
__global__ __launch_bounds__(256)
void k_slos(const float* __restrict__ x) {
    __shared__ float4 Ua[MODES][NPH];
    __shared__ float4 Ub[MODES][NPH];
    __shared__ float4 ampA[716][2];      // zero slot at 715 (level-4 padding)
    __shared__ float4 ampB[220][2];

    const int b0 = blockIdx.x * 4;
    const int tid = threadIdx.x;
    const int r = tid / 5, c = tid % 5;

    if (tid < 50) {
        const float TP = 6.28318530717958647692f;
        float s0, c0, s1, c1, s2, c2, s3, c3;
        sincosf(TP * x[(b0 + 0) * MODES + c], &s0, &c0);
        sincosf(TP * x[(b0 + 1) * MODES + c], &s1, &c1);
        sincosf(TP * x[(b0 + 2) * MODES + c], &s2, &c2);
        sincosf(TP * x[(b0 + 3) * MODES + c], &s3, &c3);
        float2 m = g_M[r][c];
        Ua[r][c] = make_float4(m.x * c0 - m.y * s0, m.x * s0 + m.y * c0,
                               m.x * c1 - m.y * s1, m.x * s1 + m.y * c1);
        Ub[r][c] = make_float4(m.x * c2 - m.y * s2, m.x * s2 + m.y * c2,
                               m.x * c3 - m.y * s3, m.x * s3 + m.y * c3);
    }
    if (tid == 0) {
        ampA[0][0] = make_float4(1.f, 0.f, 1.f, 0.f);
        ampA[0][1] = make_float4(1.f, 0.f, 1.f, 0.f);
        float4 z = make_float4(0.f, 0.f, 0.f, 0.f);
        ampA[715][0] = z; ampA[715][1] = z;   // stays zero (levels write <715)
    }
    __syncthreads();

    slos_lvl(ampA, ampB, g_T.meta + 0,   g_T.edges + 0,    10,  tid, Ua, Ub, 0);
    slos_lvl(ampB, ampA, g_T.meta + 10,  g_T.edges + 10,   55,  tid, Ua, Ub, 1);
    slos_lvl(ampA, ampB, g_T.meta + 65,  g_T.edges + 110,  220, tid, Ua, Ub, 2);
    slos_lvl(ampB, ampA, g_T.meta + 285, g_T.edges + 660,  715, tid, Ua, Ub, 3);

    // level 4: uniform 5 edges/target, t-ordered, branchless unrolled
    unsigned* po0 = g_pack + (size_t)b0 * KPAD;
    unsigned* po1 = po0 + KPAD;
    unsigned* po2 = po1 + KPAD;
    unsigned* po3 = po2 + KPAD;
    const unsigned* edges = g_T.edges + 2860;
    for (int t = tid; t < NST5; t += 256) {
        const unsigned* ee = edges + t * 5;
        float ax0 = 0.f, ay0 = 0.f, ax1 = 0.f, ay1 = 0.f;
        float ax2 = 0.f, ay2 = 0.f, ax3 = 0.f, ay3 = 0.f;
        #pragma unroll
        for (int sl = 0; sl < 5; sl++) {
            unsigned e = ee[sl];
            int idx = e & 0xFFF;
            int j = (e >> 12) & 0xF;
            float4 a01 = ampA[idx][0];
            float4 a23 = ampA[idx][1];
            float4 u01 = Ua[j][4];
            float4 u23 = Ub[j][4];
            ax0 = fmaf(u01.x, a01.x, ax0); ax0 = fmaf(-u01.y, a01.y, ax0);
            ay0 = fmaf(u01.x, a01.y, ay0); ay0 = fmaf( u01.y, a01.x, ay0);
            ax1 = fmaf(u01.z, a01.z, ax1); ax1 = fmaf(-u01.w, a01.w, ax1);
            ay1 = fmaf(u01.z, a01.w, ay1); ay1 = fmaf( u01.w, a01.z, ay1);
            ax2 = fmaf(u23.x, a23.x, ax2); ax2 = fmaf(-u23.y, a23.y, ax2);
            ay2 = fmaf(u23.x, a23.y, ay2); ay2 = fmaf( u23.y, a23.x, ay2);
            ax3 = fmaf(u23.z, a23.z, ax3); ax3 = fmaf(-u23.w, a23.w, ax3);
            ay3 = fmaf(u23.z, a23.w, ay3); ay3 = fmaf( u23.w, a23.z, ay3);
        }
        float c2v = g_T.c2[t];
        float v[4] = {c2v * (ax0 * ax0 + ay0 * ay0),
                      c2v * (ax1 * ax1 + ay1 * ay1),
                      c2v * (ax2 * ax2 + ay2 * ay2),
                      c2v * (ax3 * ax3 + ay3 * ay3)};
        unsigned pk[4];
        #pragma unroll
        for (int q = 0; q < 4; q++) {
            unsigned short hi = f2bf(v[q]);
            unsigned short lo = f2bf(v[q] - bf2f(hi));
            pk[q] = (unsigned)hi | ((unsigned)lo << 16);
        }
        po0[t] = pk[0];
        po1[t] = pk[1];
        po2[t] = pk[2];
        po3[t] = pk[3];
    }
    for (int t = NST5 + tid; t < KPAD; t += 256) {
        po0[t] = 0u; po1[t] = 0u; po2[t] = 0u; po3[t] = 0u;
    }
}

// ---------- MFMA GEMM: g_part[kc] = P x W, packed-u32 A ----------
// grid (64,8) = 512 blocks = 2/CU, 4 waves; per-block K-chunk 256 (KSPLIT=8
// halves the partials round-trip: 16.8->8.4MB each way).
// Frags: A row=ln&15, k=(ln>>4)*8+i; B col=ln&15 same k;
// D col=ln&15, row=(ln>>4)*4+reg  [m89-verified mapping].
__global__ __launch_bounds__(256)
void k_gemm_mfma() {
    const int bm = blockIdx.x;
    const int kc = blockIdx.y;
    const int wv = threadIdx.x >> 6;
    const int ln = threadIdx.x & 63;
    const int lc = ln & 15;
    const int kg = (ln >> 4) * 8;
    const int row = bm * 64 + wv * 16 + lc;
    const int ks = kc * 252;
    const int ke = (ks + 252 < KPAD) ? ks + 252 : KPAD;   // 252*8 = 2016

    f32x4 acc[4] = {f32x4{0.f, 0.f, 0.f, 0.f}, f32x4{0.f, 0.f, 0.f, 0.f},
                    f32x4{0.f, 0.f, 0.f, 0.f}, f32x4{0.f, 0.f, 0.f, 0.f}};
    const unsigned* pA = g_pack + (size_t)row * KPAD;

    for (int k0 = ks; k0 < ke; k0 += 28) {   // 9 steps of 28 = 252; 28>=... 
        // NOTE: K-step must be 32 for the 16x16x32 MFMA; use 32 with tail guard
        break;
    }
    for (int k0 = ks; k0 < ke; k0 += 32) {
        int kw = ke - k0;                     // may be 28 at chunk tail? no:
        (void)kw;                             // 252 % 32 != 0 -> handled below
        break;
    }
    // 252 is not a multiple of 32; use 32-steps over [ks, ke) with the last
    // step clamped via zero-padded reads from a 32-aligned staging in regs.
    // Simplest correct approach: iterate 32-steps over the 32-aligned cover
    // [ks & ~31, (ke+31) & ~31) and mask out-of-chunk ks by zeroing A frags.
    for (int k0 = (ks & ~31); k0 < ((ke + 31) & ~31); k0 += 32) {
        uint4 w0, w1;
        const int base = k0 + kg;
        // guard: base..base+7 within [0,KPAD) always (KPAD mult of 32), but
        // must be within [ks,ke) to belong to this chunk; else contribute 0.
        bool inA = (k0 >= ks) && (k0 + 32 <= ke);
        if (inA) {
            w0 = *(const uint4*)(pA + base);
            w1 = *(const uint4*)(pA + base + 4);
        } else {
            // partial step: elementwise guard
            unsigned tmp[8];
            #pragma unroll
            for (int i = 0; i < 8; i++) {
                int kk = base + ((i < 4) ? i : (i - 4) + 4);   // base+i
                kk = base + i;
                tmp[i] = (kk >= ks && kk < ke) ? pA[kk] : 0u;
            }
            w0 = make_uint4(tmp[0], tmp[1], tmp[2], tmp[3]);
            w1 = make_uint4(tmp[4], tmp[5], tmp[6], tmp[7]);
        }
        unsigned pw[8] = {w0.x, w0.y, w0.z, w0.w, w1.x, w1.y, w1.z, w1.w};
        bf16x8 ahi, alo;
        #pragma unroll
        for (int i = 0; i < 8; i++) {
            ahi[i] = (short)(pw[i] & 0xFFFFu);
            alo[i] = (short)(pw[i] >> 16);
        }
        #pragma unroll
        for (int n = 0; n < 4; n++) {
            const unsigned short* pBh = g_WhiT + (size_t)(n * 16 + lc) * KPAD + base;
            const unsigned short* pBl = g_WloT + (size_t)(n * 16 + lc) * KPAD + base;
            bf16x8 bhi = *(const bf16x8*)pBh;
            bf16x8 blo = *(const bf16x8*)pBl;
            acc[n] = __builtin_amdgcn_mfma_f32_16x16x32_bf16(ahi, bhi, acc[n], 0, 0, 0);
            acc[n] = __builtin_amdgcn_mfma_f32_16x16x32_bf16(ahi, blo, acc[n], 0, 0, 0);
            acc[n] = __builtin_amdgcn_mfma_f32_16x16x32_bf16(alo, bhi, acc[n], 0, 0, 0);
        }
    }

    float* po = g_part + ((size_t)kc * BATCH + bm * 64 + wv * 16) * 64;
    #pragma unroll
    for (int n = 0; n < 4; n++)
        #pragma unroll
        for (int i = 0; i < 4; i++)
            po[(size_t)((ln >> 4) * 4 + i) * 64 + n * 16 + lc] = acc[n][i];
}

// ---------- reduce KSPLIT partials + bias ----------
__global__ __launch_bounds__(256)
void k_reduce(const float* __restrict__ bias, float* __restrict__ out) {
    int i = blockIdx.x * 256 + threadIdx.x;
    const int TOT = BATCH * 64;
    if (i < TOT) {
        float v = bias[i & 63];
        #pragma unroll
        for (int m = 0; m < KSPLIT; m++) v += g_part[(size_t)m * TOT + i];
        out[i] = v;
    }
}

extern "C" void kernel_launch(void* const* d_in, const int* in_sizes, int n_in,
                              void* d_out, int out_size, void* d_ws, size_t ws_size,
                              hipStream_t stream) {
    const float* x     = (const float*)d_in[0];
    const float* theta = (const float*)d_in[1];
    const float* W     = (const float*)d_in[2];
    const float* bias  = (const float*)d_in[3];
    float* out = (float*)d_out;
    (void)d_ws; (void)ws_size; (void)in_sizes; (void)n_in; (void)out_size;

    k_prep<<<505, 256, 0, stream>>>(theta, W);
    k_slos<<<BATCH / 4, 256, 0, stream>>>(x);
    k_gemm_mfma<<<dim3(64, KSPLIT), 256, 0, stream>>>();
    k_reduce<<<1024, 256, 0, stream>>>(bias, out);
}

// Round 31
// 54.878 us; speedup vs baseline: 1.0366x; 1.0366x over previous
//
#include <hip/hip_runtime.h>

#define MODES 10
#define NPH 5
#define DEPTH 10
#define NST5 2002
#define KPAD 2016
#define BATCH 4096
#define KSPLIT 16

typedef __attribute__((ext_vector_type(8))) short bf16x8;
typedef __attribute__((ext_vector_type(4))) float f32x4;

// ============ COMPILE-TIME transition tables ============
// Levels 0-3: degree-bucketed compact CSR (divergence-free level steps).
// Level 4: t-ordered, UNIFORM 5 edges/target (padded with zero-amp slot 715).
struct DevTables {
    unsigned meta[1000];       // levels 0-3 only
    unsigned edges[2860 + NST5 * 5];
    float c2[NST5];
};

constexpr DevTables build_tables() {
    DevTables T{};
    const int sizes[6] = {1, 10, 55, 220, 715, 2002};
    const int mb[5] = {0, 10, 65, 285, 1000};
    const int eb[5] = {0, 10, 110, 660, 2860};
    const float fact[6] = {1.f, 1.f, 2.f, 6.f, 24.f, 120.f};

    unsigned prev[715] = {};
    unsigned cur[2002] = {};
    int dd[2002] = {};
    int s[10] = {};
    int prevN = 1;
    prev[0] = 0u;

    for (int lvl = 1; lvl <= 5; ++lvl) {
        const int k = lvl - 1;
        const int N = sizes[lvl];
        int cnt[5] = {0, 0, 0, 0, 0};
        for (int p = 0; p < 10; ++p) s[p] = 0;
        s[0] = lvl;
        for (int t = 0; t < N; ++t) {
            unsigned P = 0;
            int d = 0;
            for (int p = 0; p < 10; ++p) {
                P |= (unsigned)s[p] << (3 * (9 - p));
                d += (s[p] > 0) ? 1 : 0;
            }
            cur[t] = P;
            dd[t] = d;
            cnt[d - 1] += 1;
            int p = 8;
            while (p >= 0 && s[p] == 0) --p;
            if (p >= 0) {
                int rest = 1;
                for (int q = p + 1; q < 10; ++q) { rest += s[q]; s[q] = 0; }
                s[p] -= 1;
                s[p + 1] = rest;
            }
        }
        int bp[5] = {}, be[5] = {};
        {
            int pp = 0, ee = 0;
            for (int d = 0; d < 5; ++d) {
                bp[d] = pp; be[d] = ee;
                pp += cnt[d]; ee += cnt[d] * (d + 1);
            }
        }
        for (int p = 0; p < 10; ++p) s[p] = 0;
        s[0] = lvl;
        for (int t = 0; t < N; ++t) {
            const int d = dd[t];
            int pos = 0, eo = 0;
            if (lvl == 5) {                 // uniform: 5 slots at t*5
                pos = -1;
                eo = t * 5;
            } else {                        // bucketed
                pos = mb[k] + bp[d - 1];
                eo = be[d - 1];
                bp[d - 1] += 1;
                be[d - 1] += d;
                T.meta[pos] = (unsigned)t | ((unsigned)d << 11) | ((unsigned)eo << 14);
            }
            int w = 0;
            for (int j = 0; j < 10; ++j) {
                if (s[j] > 0) {
                    unsigned pp2 = cur[t] - (1u << (3 * (9 - j)));
                    int lo = 0, hi = prevN - 1;
                    while (lo < hi) {
                        int mid = (lo + hi) >> 1;
                        if (prev[mid] > pp2) lo = mid + 1; else hi = mid;
                    }
                    T.edges[eb[k] + eo + w] = (unsigned)lo | ((unsigned)j << 12);
                    w += 1;
                }
            }
            if (lvl == 5) {
                for (; w < 5; ++w) T.edges[eb[k] + eo + w] = 715u;  // zero amp
                float c2 = 1.f;
                for (int j = 0; j < 10; ++j) c2 *= fact[s[j]];
                T.c2[t] = c2;
            }
            int p = 8;
            while (p >= 0 && s[p] == 0) --p;
            if (p >= 0) {
                int rest = 1;
                for (int q = p + 1; q < 10; ++q) { rest += s[q]; s[q] = 0; }
                s[p] -= 1;
                s[p + 1] = rest;
            }
        }
        if (lvl < 5) {
            for (int t = 0; t < N; ++t) prev[t] = cur[t];
            prevN = N;
        }
    }
    return T;
}

__device__ const DevTables g_T = build_tables();

// ---------- runtime scratch ----------
// A operand: PACKED u32 = bf16(hi) | bf16(lo)<<16 per element (R28/R29 best).
__device__ __align__(16) unsigned g_pack[(size_t)BATCH * KPAD];
__device__ __align__(16) unsigned short g_WhiT[64 * KPAD];   // [col][k]
__device__ __align__(16) unsigned short g_WloT[64 * KPAD];
__device__ float2 g_M[MODES][NPH];
__device__ float g_part[(size_t)KSPLIT * BATCH * 64];

__device__ __forceinline__ unsigned short f2bf(float f) {
    unsigned u = __float_as_uint(f);
    unsigned r = (u + 0x7FFF + ((u >> 16) & 1)) >> 16;   // RNE
    return (unsigned short)r;
}
__device__ __forceinline__ float bf2f(unsigned short h) {
    return __uint_as_float((unsigned)h << 16);
}

// ---------- prep: blocks 0..503 split W; block 504 builds g_M ----------
__global__ __launch_bounds__(256)
void k_prep(const float* __restrict__ theta, const float* __restrict__ W) {
    const int tid = threadIdx.x;
    if (blockIdx.x == 504) {
        __shared__ float2 Ush[MODES][NPH];
        const int r = tid / 5, c = tid % 5;
        const bool act = (tid < 50);
        float2 val = make_float2((act && r == c) ? 1.f : 0.f, 0.f);
        for (int l = 0; l < DEPTH; l++) {
            if (act && l > 0) {
                float ang = theta[(l - 1) * MODES + r];
                float s_, c_; sincosf(ang, &s_, &c_);
                float nx = val.x * c_ - val.y * s_;
                float ny = val.x * s_ + val.y * c_;
                val = make_float2(nx, ny);
            }
            if (act) Ush[r][c] = val;
            __syncthreads();
            float2 nv = val;
            if (act) {
                int o = l & 1;
                int lo = r - o;
                int partner = o + (lo ^ 1);
                if (lo >= 0 && partner < MODES) {
                    float2 pb = Ush[partner][c];
                    const float inv = 0.70710678118654752f;
                    nv.x = inv * (val.x - pb.y);
                    nv.y = inv * (val.y + pb.x);
                }
            }
            __syncthreads();
            val = nv;
        }
        if (act) g_M[r][c] = val;
        return;
    }
    int id = blockIdx.x * 256 + tid;       // 504*256 = 129024 = 64*2016
    int k = id / 64, c = id % 64;
    float w = (k < NST5) ? W[(size_t)k * 64 + c] : 0.f;
    unsigned short hi = f2bf(w);
    unsigned short lo = f2bf(w - bf2f(hi));
    g_WhiT[(size_t)c * KPAD + k] = hi;
    g_WloT[(size_t)c * KPAD + k] = lo;
}

// ---------- SLOS level step, compact edges, 4 batch elems packed ----------
__device__ __forceinline__ void slos_lvl(const float4 (*__restrict__ src)[2],
                                         float4 (*__restrict__ dst)[2],
                                         const unsigned* __restrict__ meta,
                                         const unsigned* __restrict__ edges,
                                         int N, int tid,
                                         const float4 (*Ua)[NPH],
                                         const float4 (*Ub)[NPH], int k) {
    for (int pos = tid; pos < N; pos += 256) {
        unsigned m = meta[pos];
        int t = m & 0x7FF;
        int d = (m >> 11) & 0x7;
        const unsigned* ee = edges + (m >> 14);
        float ax0 = 0.f, ay0 = 0.f, ax1 = 0.f, ay1 = 0.f;
        float ax2 = 0.f, ay2 = 0.f, ax3 = 0.f, ay3 = 0.f;
        for (int sl = 0; sl < d; sl++) {
            unsigned e = ee[sl];
            int idx = e & 0xFFF;
            int j = (e >> 12) & 0xF;
            float4 a01 = src[idx][0];
            float4 a23 = src[idx][1];
            float4 u01 = Ua[j][k];
            float4 u23 = Ub[j][k];
            ax0 = fmaf(u01.x, a01.x, ax0); ax0 = fmaf(-u01.y, a01.y, ax0);
            ay0 = fmaf(u01.x, a01.y, ay0); ay0 = fmaf( u01.y, a01.x, ay0);
            ax1 = fmaf(u01.z, a01.z, ax1); ax1 = fmaf(-u01.w, a01.w, ax1);
            ay1 = fmaf(u01.z, a01.w, ay1); ay1 = fmaf( u01.w, a01.z, ay1);
            ax2 = fmaf(u23.x, a23.x, ax2); ax2 = fmaf(-u23.y, a23.y, ax2);
            ay2 = fmaf(u23.x, a23.y, ay2); ay2 = fmaf( u23.y, a23.x, ay2);
            ax3 = fmaf(u23.z, a23.z, ax3); ax3 = fmaf(-u23.w, a23.w, ax3);
            ay3 = fmaf(u23.z, a23.w, ay3); ay3 = fmaf( u23.w, a23.z, ay3);
        }
        dst[t][0] = make_float4(ax0, ay0, ax1, ay1);
        dst[t][1] = make_float4(ax2, ay2, ax3, ay3);
    }
    __syncthreads();
}

// ---------- SLOS, 4 batch elements per block; packed u32 hi|lo out ----------
__global__ __launch_bounds__(256)
void k_slos(const float* __restrict__ x) {
    __shared__ float4 Ua[MODES][NPH];
    __shared__ float4 Ub[MODES][NPH];
    __shared__ float4 ampA[716][2];      // zero slot at 715 (level-4 padding)
    __shared__ float4 ampB[220][2];

    const int b0 = blockIdx.x * 4;
    const int tid = threadIdx.x;
    const int r = tid / 5, c = tid % 5;

    if (tid < 50) {
        const float TP = 6.28318530717958647692f;
        float s0, c0, s1, c1, s2, c2, s3, c3;
        sincosf(TP * x[(b0 + 0) * MODES + c], &s0, &c0);
        sincosf(TP * x[(b0 + 1) * MODES + c], &s1, &c1);
        sincosf(TP * x[(b0 + 2) * MODES + c], &s2, &c2);
        sincosf(TP * x[(b0 + 3) * MODES + c], &s3, &c3);
        float2 m = g_M[r][c];
        Ua[r][c] = make_float4(m.x * c0 - m.y * s0, m.x * s0 + m.y * c0,
                               m.x * c1 - m.y * s1, m.x * s1 + m.y * c1);
        Ub[r][c] = make_float4(m.x * c2 - m.y * s2, m.x * s2 + m.y * c2,
                               m.x * c3 - m.y * s3, m.x * s3 + m.y * c3);
    }
    if (tid == 0) {
        ampA[0][0] = make_float4(1.f, 0.f, 1.f, 0.f);
        ampA[0][1] = make_float4(1.f, 0.f, 1.f, 0.f);
        float4 z = make_float4(0.f, 0.f, 0.f, 0.f);
        ampA[715][0] = z; ampA[715][1] = z;   // stays zero (levels write <715)
    }
    __syncthreads();

    slos_lvl(ampA, ampB, g_T.meta + 0,   g_T.edges + 0,    10,  tid, Ua, Ub, 0);
    slos_lvl(ampB, ampA, g_T.meta + 10,  g_T.edges + 10,   55,  tid, Ua, Ub, 1);
    slos_lvl(ampA, ampB, g_T.meta + 65,  g_T.edges + 110,  220, tid, Ua, Ub, 2);
    slos_lvl(ampB, ampA, g_T.meta + 285, g_T.edges + 660,  715, tid, Ua, Ub, 3);

    // level 4: uniform 5 edges/target, t-ordered, branchless unrolled
    unsigned* po0 = g_pack + (size_t)b0 * KPAD;
    unsigned* po1 = po0 + KPAD;
    unsigned* po2 = po1 + KPAD;
    unsigned* po3 = po2 + KPAD;
    const unsigned* edges = g_T.edges + 2860;
    for (int t = tid; t < NST5; t += 256) {
        const unsigned* ee = edges + t * 5;
        float ax0 = 0.f, ay0 = 0.f, ax1 = 0.f, ay1 = 0.f;
        float ax2 = 0.f, ay2 = 0.f, ax3 = 0.f, ay3 = 0.f;
        #pragma unroll
        for (int sl = 0; sl < 5; sl++) {
            unsigned e = ee[sl];
            int idx = e & 0xFFF;
            int j = (e >> 12) & 0xF;
            float4 a01 = ampA[idx][0];
            float4 a23 = ampA[idx][1];
            float4 u01 = Ua[j][4];
            float4 u23 = Ub[j][4];
            ax0 = fmaf(u01.x, a01.x, ax0); ax0 = fmaf(-u01.y, a01.y, ax0);
            ay0 = fmaf(u01.x, a01.y, ay0); ay0 = fmaf( u01.y, a01.x, ay0);
            ax1 = fmaf(u01.z, a01.z, ax1); ax1 = fmaf(-u01.w, a01.w, ax1);
            ay1 = fmaf(u01.z, a01.w, ay1); ay1 = fmaf( u01.w, a01.z, ay1);
            ax2 = fmaf(u23.x, a23.x, ax2); ax2 = fmaf(-u23.y, a23.y, ax2);
            ay2 = fmaf(u23.x, a23.y, ay2); ay2 = fmaf( u23.y, a23.x, ay2);
            ax3 = fmaf(u23.z, a23.z, ax3); ax3 = fmaf(-u23.w, a23.w, ax3);
            ay3 = fmaf(u23.z, a23.w, ay3); ay3 = fmaf( u23.w, a23.z, ay3);
        }
        float c2v = g_T.c2[t];
        float v[4] = {c2v * (ax0 * ax0 + ay0 * ay0),
                      c2v * (ax1 * ax1 + ay1 * ay1),
                      c2v * (ax2 * ax2 + ay2 * ay2),
                      c2v * (ax3 * ax3 + ay3 * ay3)};
        unsigned pk[4];
        #pragma unroll
        for (int q = 0; q < 4; q++) {
            unsigned short hi = f2bf(v[q]);
            unsigned short lo = f2bf(v[q] - bf2f(hi));
            pk[q] = (unsigned)hi | ((unsigned)lo << 16);
        }
        po0[t] = pk[0];
        po1[t] = pk[1];
        po2[t] = pk[2];
        po3[t] = pk[3];
    }
    for (int t = NST5 + tid; t < KPAD; t += 256) {
        po0[t] = 0u; po1[t] = 0u; po2[t] = 0u; po3[t] = 0u;
    }
}

// ---------- MFMA GEMM: g_part[kc] = P x W, packed-u32 A ----------
// Proven geometry (R23/R28/R29: best): grid (64,16) = 1024 blocks, 4 waves.
// Frags: A row=ln&15, k=(ln>>4)*8+i; B col=ln&15 same k;
// D col=ln&15, row=(ln>>4)*4+reg  [m89-verified mapping].
__global__ __launch_bounds__(256)
void k_gemm_mfma() {
    const int bm = blockIdx.x;
    const int kc = blockIdx.y;
    const int wv = threadIdx.x >> 6;
    const int ln = threadIdx.x & 63;
    const int lc = ln & 15;
    const int kg = (ln >> 4) * 8;
    const int row = bm * 64 + wv * 16 + lc;
    const int ks = kc * 128;
    const int ke = (ks + 128 < KPAD) ? ks + 128 : KPAD;   // kc=15 -> 96

    f32x4 acc[4] = {f32x4{0.f, 0.f, 0.f, 0.f}, f32x4{0.f, 0.f, 0.f, 0.f},
                    f32x4{0.f, 0.f, 0.f, 0.f}, f32x4{0.f, 0.f, 0.f, 0.f}};
    const unsigned* pA = g_pack + (size_t)row * KPAD;

    for (int k0 = ks; k0 < ke; k0 += 32) {
        uint4 w0 = *(const uint4*)(pA + k0 + kg);
        uint4 w1 = *(const uint4*)(pA + k0 + kg + 4);
        unsigned pw[8] = {w0.x, w0.y, w0.z, w0.w, w1.x, w1.y, w1.z, w1.w};
        bf16x8 ahi, alo;
        #pragma unroll
        for (int i = 0; i < 8; i++) {
            ahi[i] = (short)(pw[i] & 0xFFFFu);
            alo[i] = (short)(pw[i] >> 16);
        }
        #pragma unroll
        for (int n = 0; n < 4; n++) {
            const unsigned short* pBh = g_WhiT + (size_t)(n * 16 + lc) * KPAD + k0 + kg;
            const unsigned short* pBl = g_WloT + (size_t)(n * 16 + lc) * KPAD + k0 + kg;
            bf16x8 bhi = *(const bf16x8*)pBh;
            bf16x8 blo = *(const bf16x8*)pBl;
            acc[n] = __builtin_amdgcn_mfma_f32_16x16x32_bf16(ahi, bhi, acc[n], 0, 0, 0);
            acc[n] = __builtin_amdgcn_mfma_f32_16x16x32_bf16(ahi, blo, acc[n], 0, 0, 0);
            acc[n] = __builtin_amdgcn_mfma_f32_16x16x32_bf16(alo, bhi, acc[n], 0, 0, 0);
        }
    }

    float* po = g_part + ((size_t)kc * BATCH + bm * 64 + wv * 16) * 64;
    #pragma unroll
    for (int n = 0; n < 4; n++)
        #pragma unroll
        for (int i = 0; i < 4; i++)
            po[(size_t)((ln >> 4) * 4 + i) * 64 + n * 16 + lc] = acc[n][i];
}

// ---------- reduce KSPLIT partials + bias ----------
__global__ __launch_bounds__(256)
void k_reduce(const float* __restrict__ bias, float* __restrict__ out) {
    int i = blockIdx.x * 256 + threadIdx.x;
    const int TOT = BATCH * 64;
    if (i < TOT) {
        float v = bias[i & 63];
        #pragma unroll
        for (int m = 0; m < KSPLIT; m++) v += g_part[(size_t)m * TOT + i];
        out[i] = v;
    }
}

extern "C" void kernel_launch(void* const* d_in, const int* in_sizes, int n_in,
                              void* d_out, int out_size, void* d_ws, size_t ws_size,
                              hipStream_t stream) {
    const float* x     = (const float*)d_in[0];
    const float* theta = (const float*)d_in[1];
    const float* W     = (const float*)d_in[2];
    const float* bias  = (const float*)d_in[3];
    float* out = (float*)d_out;
    (void)d_ws; (void)ws_size; (void)in_sizes; (void)n_in; (void)out_size;

    k_prep<<<505, 256, 0, stream>>>(theta, W);
    k_slos<<<BATCH / 4, 256, 0, stream>>>(x);
    k_gemm_mfma<<<dim3(64, KSPLIT), 256, 0, stream>>>();
    k_reduce<<<1024, 256, 0, stream>>>(bias, out);
}

// Round 32
// 48.436 us; speedup vs baseline: 1.1744x; 1.1330x over previous
//
#include <hip/hip_runtime.h>

#define MODES 10
#define NPH 5
#define DEPTH 10
#define NST5 2002
#define KPAD 2016
#define BATCH 4096
#define KSPLIT 16

typedef __attribute__((ext_vector_type(8))) short bf16x8;
typedef __attribute__((ext_vector_type(4))) float f32x4;

// ============ COMPILE-TIME transition tables ============
// Levels 0-3: degree-bucketed compact CSR (divergence-free level steps).
// Level 4: t-ordered, UNIFORM 5 edges/target (padded with zero-amp slot 715).
struct DevTables {
    unsigned meta[1000];       // levels 0-3 only
    unsigned edges[2860 + NST5 * 5];
    float c2[NST5];
};

constexpr DevTables build_tables() {
    DevTables T{};
    const int sizes[6] = {1, 10, 55, 220, 715, 2002};
    const int mb[5] = {0, 10, 65, 285, 1000};
    const int eb[5] = {0, 10, 110, 660, 2860};
    const float fact[6] = {1.f, 1.f, 2.f, 6.f, 24.f, 120.f};

    unsigned prev[715] = {};
    unsigned cur[2002] = {};
    int dd[2002] = {};
    int s[10] = {};
    int prevN = 1;
    prev[0] = 0u;

    for (int lvl = 1; lvl <= 5; ++lvl) {
        const int k = lvl - 1;
        const int N = sizes[lvl];
        int cnt[5] = {0, 0, 0, 0, 0};
        for (int p = 0; p < 10; ++p) s[p] = 0;
        s[0] = lvl;
        for (int t = 0; t < N; ++t) {
            unsigned P = 0;
            int d = 0;
            for (int p = 0; p < 10; ++p) {
                P |= (unsigned)s[p] << (3 * (9 - p));
                d += (s[p] > 0) ? 1 : 0;
            }
            cur[t] = P;
            dd[t] = d;
            cnt[d - 1] += 1;
            int p = 8;
            while (p >= 0 && s[p] == 0) --p;
            if (p >= 0) {
                int rest = 1;
                for (int q = p + 1; q < 10; ++q) { rest += s[q]; s[q] = 0; }
                s[p] -= 1;
                s[p + 1] = rest;
            }
        }
        int bp[5] = {}, be[5] = {};
        {
            int pp = 0, ee = 0;
            for (int d = 0; d < 5; ++d) {
                bp[d] = pp; be[d] = ee;
                pp += cnt[d]; ee += cnt[d] * (d + 1);
            }
        }
        for (int p = 0; p < 10; ++p) s[p] = 0;
        s[0] = lvl;
        for (int t = 0; t < N; ++t) {
            const int d = dd[t];
            int pos = 0, eo = 0;
            if (lvl == 5) {                 // uniform: 5 slots at t*5
                pos = -1;
                eo = t * 5;
            } else {                        // bucketed
                pos = mb[k] + bp[d - 1];
                eo = be[d - 1];
                bp[d - 1] += 1;
                be[d - 1] += d;
                T.meta[pos] = (unsigned)t | ((unsigned)d << 11) | ((unsigned)eo << 14);
            }
            int w = 0;
            for (int j = 0; j < 10; ++j) {
                if (s[j] > 0) {
                    unsigned pp2 = cur[t] - (1u << (3 * (9 - j)));
                    int lo = 0, hi = prevN - 1;
                    while (lo < hi) {
                        int mid = (lo + hi) >> 1;
                        if (prev[mid] > pp2) lo = mid + 1; else hi = mid;
                    }
                    T.edges[eb[k] + eo + w] = (unsigned)lo | ((unsigned)j << 12);
                    w += 1;
                }
            }
            if (lvl == 5) {
                for (; w < 5; ++w) T.edges[eb[k] + eo + w] = 715u;  // zero amp
                float c2 = 1.f;
                for (int j = 0; j < 10; ++j) c2 *= fact[s[j]];
                T.c2[t] = c2;
            }
            int p = 8;
            while (p >= 0 && s[p] == 0) --p;
            if (p >= 0) {
                int rest = 1;
                for (int q = p + 1; q < 10; ++q) { rest += s[q]; s[q] = 0; }
                s[p] -= 1;
                s[p + 1] = rest;
            }
        }
        if (lvl < 5) {
            for (int t = 0; t < N; ++t) prev[t] = cur[t];
            prevN = N;
        }
    }
    return T;
}

__device__ const DevTables g_T = build_tables();

// ---------- runtime scratch ----------
// A operand: PACKED u32 = bf16(hi) | bf16(lo)<<16 per element (R28/R29 best).
__device__ __align__(16) unsigned g_pack[(size_t)BATCH * KPAD];
__device__ __align__(16) unsigned short g_WhiT[64 * KPAD];   // [col][k]
__device__ __align__(16) unsigned short g_WloT[64 * KPAD];
__device__ float2 g_M[MODES][NPH];
__device__ float g_part[(size_t)KSPLIT * BATCH * 64];

__device__ __forceinline__ unsigned short f2bf(float f) {
    unsigned u = __float_as_uint(f);
    unsigned r = (u + 0x7FFF + ((u >> 16) & 1)) >> 16;   // RNE
    return (unsigned short)r;
}
__device__ __forceinline__ float bf2f(unsigned short h) {
    return __uint_as_float((unsigned)h << 16);
}

// ---------- prep: blocks 0..503 split W; block 504 builds g_M ----------
__global__ __launch_bounds__(256)
void k_prep(const float* __restrict__ theta, const float* __restrict__ W) {
    const int tid = threadIdx.x;
    if (blockIdx.x == 504) {
        __shared__ float2 Ush[MODES][NPH];
        const int r = tid / 5, c = tid % 5;
        const bool act = (tid < 50);
        float2 val = make_float2((act && r == c) ? 1.f : 0.f, 0.f);
        for (int l = 0; l < DEPTH; l++) {
            if (act && l > 0) {
                float ang = theta[(l - 1) * MODES + r];
                float s_, c_; sincosf(ang, &s_, &c_);
                float nx = val.x * c_ - val.y * s_;
                float ny = val.x * s_ + val.y * c_;
                val = make_float2(nx, ny);
            }
            if (act) Ush[r][c] = val;
            __syncthreads();
            float2 nv = val;
            if (act) {
                int o = l & 1;
                int lo = r - o;
                int partner = o + (lo ^ 1);
                if (lo >= 0 && partner < MODES) {
                    float2 pb = Ush[partner][c];
                    const float inv = 0.70710678118654752f;
                    nv.x = inv * (val.x - pb.y);
                    nv.y = inv * (val.y + pb.x);
                }
            }
            __syncthreads();
            val = nv;
        }
        if (act) g_M[r][c] = val;
        return;
    }
    int id = blockIdx.x * 256 + tid;       // 504*256 = 129024 = 64*2016
    int k = id / 64, c = id % 64;
    float w = (k < NST5) ? W[(size_t)k * 64 + c] : 0.f;
    unsigned short hi = f2bf(w);
    unsigned short lo = f2bf(w - bf2f(hi));
    g_WhiT[(size_t)c * KPAD + k] = hi;
    g_WloT[(size_t)c * KPAD + k] = lo;
}

// ---------- SLOS level step, compact edges, 4 batch elems packed ----------
__device__ __forceinline__ void slos_lvl(const float4 (*__restrict__ src)[2],
                                         float4 (*__restrict__ dst)[2],
                                         const unsigned* __restrict__ meta,
                                         const unsigned* __restrict__ edges,
                                         int N, int tid,
                                         const float4 (*Ua)[NPH],
                                         const float4 (*Ub)[NPH], int k) {
    for (int pos = tid; pos < N; pos += 256) {
        unsigned m = meta[pos];
        int t = m & 0x7FF;
        int d = (m >> 11) & 0x7;
        const unsigned* ee = edges + (m >> 14);
        float ax0 = 0.f, ay0 = 0.f, ax1 = 0.f, ay1 = 0.f;
        float ax2 = 0.f, ay2 = 0.f, ax3 = 0.f, ay3 = 0.f;
        for (int sl = 0; sl < d; sl++) {
            unsigned e = ee[sl];
            int idx = e & 0xFFF;
            int j = (e >> 12) & 0xF;
            float4 a01 = src[idx][0];
            float4 a23 = src[idx][1];
            float4 u01 = Ua[j][k];
            float4 u23 = Ub[j][k];
            ax0 = fmaf(u01.x, a01.x, ax0); ax0 = fmaf(-u01.y, a01.y, ax0);
            ay0 = fmaf(u01.x, a01.y, ay0); ay0 = fmaf( u01.y, a01.x, ay0);
            ax1 = fmaf(u01.z, a01.z, ax1); ax1 = fmaf(-u01.w, a01.w, ax1);
            ay1 = fmaf(u01.z, a01.w, ay1); ay1 = fmaf( u01.w, a01.z, ay1);
            ax2 = fmaf(u23.x, a23.x, ax2); ax2 = fmaf(-u23.y, a23.y, ax2);
            ay2 = fmaf(u23.x, a23.y, ay2); ay2 = fmaf( u23.y, a23.x, ay2);
            ax3 = fmaf(u23.z, a23.z, ax3); ax3 = fmaf(-u23.w, a23.w, ax3);
            ay3 = fmaf(u23.z, a23.w, ay3); ay3 = fmaf( u23.w, a23.z, ay3);
        }
        dst[t][0] = make_float4(ax0, ay0, ax1, ay1);
        dst[t][1] = make_float4(ax2, ay2, ax3, ay3);
    }
    __syncthreads();
}

// ---------- SLOS, 4 batch elements per block; packed u32 hi|lo out ----------
__global__ __launch_bounds__(256)
void k_slos(const float* __restrict__ x) {
    __shared__ float4 Ua[MODES][NPH];
    __shared__ float4 Ub[MODES][NPH];
    __shared__ float4 ampA[716][2];      // zero slot at 715 (level-4 padding)
    __shared__ float4 ampB[220][2];

    const int b0 = blockIdx.x * 4;
    const int tid = threadIdx.x;
    const int r = tid / 5, c = tid % 5;

    if (tid < 50) {
        const float TP = 6.28318530717958647692f;
        float s0, c0, s1, c1, s2, c2, s3, c3;
        sincosf(TP * x[(b0 + 0) * MODES + c], &s0, &c0);
        sincosf(TP * x[(b0 + 1) * MODES + c], &s1, &c1);
        sincosf(TP * x[(b0 + 2) * MODES + c], &s2, &c2);
        sincosf(TP * x[(b0 + 3) * MODES + c], &s3, &c3);
        float2 m = g_M[r][c];
        Ua[r][c] = make_float4(m.x * c0 - m.y * s0, m.x * s0 + m.y * c0,
                               m.x * c1 - m.y * s1, m.x * s1 + m.y * c1);
        Ub[r][c] = make_float4(m.x * c2 - m.y * s2, m.x * s2 + m.y * c2,
                               m.x * c3 - m.y * s3, m.x * s3 + m.y * c3);
    }
    if (tid == 0) {
        ampA[0][0] = make_float4(1.f, 0.f, 1.f, 0.f);
        ampA[0][1] = make_float4(1.f, 0.f, 1.f, 0.f);
        float4 z = make_float4(0.f, 0.f, 0.f, 0.f);
        ampA[715][0] = z; ampA[715][1] = z;   // stays zero (levels write <715)
    }
    __syncthreads();

    slos_lvl(ampA, ampB, g_T.meta + 0,   g_T.edges + 0,    10,  tid, Ua, Ub, 0);
    slos_lvl(ampB, ampA, g_T.meta + 10,  g_T.edges + 10,   55,  tid, Ua, Ub, 1);
    slos_lvl(ampA, ampB, g_T.meta + 65,  g_T.edges + 110,  220, tid, Ua, Ub, 2);
    slos_lvl(ampB, ampA, g_T.meta + 285, g_T.edges + 660,  715, tid, Ua, Ub, 3);

    // level 4: uniform 5 edges/target, t-ordered, branchless unrolled
    unsigned* po0 = g_pack + (size_t)b0 * KPAD;
    unsigned* po1 = po0 + KPAD;
    unsigned* po2 = po1 + KPAD;
    unsigned* po3 = po2 + KPAD;
    const unsigned* edges = g_T.edges + 2860;
    for (int t = tid; t < NST5; t += 256) {
        const unsigned* ee = edges + t * 5;
        float ax0 = 0.f, ay0 = 0.f, ax1 = 0.f, ay1 = 0.f;
        float ax2 = 0.f, ay2 = 0.f, ax3 = 0.f, ay3 = 0.f;
        #pragma unroll
        for (int sl = 0; sl < 5; sl++) {
            unsigned e = ee[sl];
            int idx = e & 0xFFF;
            int j = (e >> 12) & 0xF;
            float4 a01 = ampA[idx][0];
            float4 a23 = ampA[idx][1];
            float4 u01 = Ua[j][4];
            float4 u23 = Ub[j][4];
            ax0 = fmaf(u01.x, a01.x, ax0); ax0 = fmaf(-u01.y, a01.y, ax0);
            ay0 = fmaf(u01.x, a01.y, ay0); ay0 = fmaf( u01.y, a01.x, ay0);
            ax1 = fmaf(u01.z, a01.z, ax1); ax1 = fmaf(-u01.w, a01.w, ax1);
            ay1 = fmaf(u01.z, a01.w, ay1); ay1 = fmaf( u01.w, a01.z, ay1);
            ax2 = fmaf(u23.x, a23.x, ax2); ax2 = fmaf(-u23.y, a23.y, ax2);
            ay2 = fmaf(u23.x, a23.y, ay2); ay2 = fmaf( u23.y, a23.x, ay2);
            ax3 = fmaf(u23.z, a23.z, ax3); ax3 = fmaf(-u23.w, a23.w, ax3);
            ay3 = fmaf(u23.z, a23.w, ay3); ay3 = fmaf( u23.w, a23.z, ay3);
        }
        float c2v = g_T.c2[t];
        float v[4] = {c2v * (ax0 * ax0 + ay0 * ay0),
                      c2v * (ax1 * ax1 + ay1 * ay1),
                      c2v * (ax2 * ax2 + ay2 * ay2),
                      c2v * (ax3 * ax3 + ay3 * ay3)};
        unsigned pk[4];
        #pragma unroll
        for (int q = 0; q < 4; q++) {
            unsigned short hi = f2bf(v[q]);
            unsigned short lo = f2bf(v[q] - bf2f(hi));
            pk[q] = (unsigned)hi | ((unsigned)lo << 16);
        }
        po0[t] = pk[0];
        po1[t] = pk[1];
        po2[t] = pk[2];
        po3[t] = pk[3];
    }
    for (int t = NST5 + tid; t < KPAD; t += 256) {
        po0[t] = 0u; po1[t] = 0u; po2[t] = 0u; po3[t] = 0u;
    }
}

// ---------- MFMA GEMM: g_part[kc] = P x W, packed-u32 A, B staged in LDS ----
// grid (64,16) = 1024 blocks (proven best), 4 waves. NEW: the block's B-chunk
// (64 cols x <=128 ks, hi+lo = 32KB) is staged into LDS ONCE (coalesced 16B
// reads; each col-chunk is 256B contiguous), removing the 8 scattered global
// B loads per k-step from the inner loop (was 10 loads : 12 MFMAs).
// LDS [col][k+8 pad]: read addr stride 272B -> 2 lanes/bank = free (m136).
// Frags: A row=ln&15, k=(ln>>4)*8+i; B col=ln&15 same k;
// D col=ln&15, row=(ln>>4)*4+reg  [m89-verified mapping].
__global__ __launch_bounds__(256)
void k_gemm_mfma() {
    __shared__ unsigned short Bh[64][136];   // [col][k-ks], +8 u16 pad
    __shared__ unsigned short Bl[64][136];

    const int bm = blockIdx.x;
    const int kc = blockIdx.y;
    const int wv = threadIdx.x >> 6;
    const int ln = threadIdx.x & 63;
    const int lc = ln & 15;
    const int kg = (ln >> 4) * 8;
    const int row = bm * 64 + wv * 16 + lc;
    const int ks = kc * 128;
    const int ke = (ks + 128 < KPAD) ? ks + 128 : KPAD;   // kc=15 -> 96 wide
    const int kw = ke - ks;                                // 128 or 96

    // ---- stage B (hi+lo) into LDS, coalesced ----
    {
        const int nch = kw / 8;              // 16B chunks per col (16 or 12)
        const int total = 64 * nch;          // 1024 or 768
        for (int cch = threadIdx.x; cch < total; cch += 256) {
            int col = cch / nch;
            int k8 = (cch % nch) * 8;
            *(uint4*)&Bh[col][k8] =
                *(const uint4*)(g_WhiT + (size_t)col * KPAD + ks + k8);
            *(uint4*)&Bl[col][k8] =
                *(const uint4*)(g_WloT + (size_t)col * KPAD + ks + k8);
        }
    }
    __syncthreads();

    f32x4 acc[4] = {f32x4{0.f, 0.f, 0.f, 0.f}, f32x4{0.f, 0.f, 0.f, 0.f},
                    f32x4{0.f, 0.f, 0.f, 0.f}, f32x4{0.f, 0.f, 0.f, 0.f}};
    const unsigned* pA = g_pack + (size_t)row * KPAD;

    for (int k0 = ks; k0 < ke; k0 += 32) {
        uint4 w0 = *(const uint4*)(pA + k0 + kg);
        uint4 w1 = *(const uint4*)(pA + k0 + kg + 4);
        unsigned pw[8] = {w0.x, w0.y, w0.z, w0.w, w1.x, w1.y, w1.z, w1.w};
        bf16x8 ahi, alo;
        #pragma unroll
        for (int i = 0; i < 8; i++) {
            ahi[i] = (short)(pw[i] & 0xFFFFu);
            alo[i] = (short)(pw[i] >> 16);
        }
        const int koff = k0 - ks + kg;
        #pragma unroll
        for (int n = 0; n < 4; n++) {
            bf16x8 bhi = *(const bf16x8*)&Bh[n * 16 + lc][koff];
            bf16x8 blo = *(const bf16x8*)&Bl[n * 16 + lc][koff];
            acc[n] = __builtin_amdgcn_mfma_f32_16x16x32_bf16(ahi, bhi, acc[n], 0, 0, 0);
            acc[n] = __builtin_amdgcn_mfma_f32_16x16x32_bf16(ahi, blo, acc[n], 0, 0, 0);
            acc[n] = __builtin_amdgcn_mfma_f32_16x16x32_bf16(alo, bhi, acc[n], 0, 0, 0);
        }
    }

    float* po = g_part + ((size_t)kc * BATCH + bm * 64 + wv * 16) * 64;
    #pragma unroll
    for (int n = 0; n < 4; n++)
        #pragma unroll
        for (int i = 0; i < 4; i++)
            po[(size_t)((ln >> 4) * 4 + i) * 64 + n * 16 + lc] = acc[n][i];
}

// ---------- reduce KSPLIT partials + bias ----------
__global__ __launch_bounds__(256)
void k_reduce(const float* __restrict__ bias, float* __restrict__ out) {
    int i = blockIdx.x * 256 + threadIdx.x;
    const int TOT = BATCH * 64;
    if (i < TOT) {
        float v = bias[i & 63];
        #pragma unroll
        for (int m = 0; m < KSPLIT; m++) v += g_part[(size_t)m * TOT + i];
        out[i] = v;
    }
}

extern "C" void kernel_launch(void* const* d_in, const int* in_sizes, int n_in,
                              void* d_out, int out_size, void* d_ws, size_t ws_size,
                              hipStream_t stream) {
    const float* x     = (const float*)d_in[0];
    const float* theta = (const float*)d_in[1];
    const float* W     = (const float*)d_in[2];
    const float* bias  = (const float*)d_in[3];
    float* out = (float*)d_out;
    (void)d_ws; (void)ws_size; (void)in_sizes; (void)n_in; (void)out_size;

    k_prep<<<505, 256, 0, stream>>>(theta, W);
    k_slos<<<BATCH / 4, 256, 0, stream>>>(x);
    k_gemm_mfma<<<dim3(64, KSPLIT), 256, 0, stream>>>();
    k_reduce<<<1024, 256, 0, stream>>>(bias, out);
}

// Round 33
// 48.366 us; speedup vs baseline: 1.1761x; 1.0015x over previous
//
#include <hip/hip_runtime.h>

#define MODES 10
#define NPH 5
#define DEPTH 10
#define NST5 2002
#define KPAD 2016
#define BATCH 4096
#define KSPLIT 16

typedef __attribute__((ext_vector_type(8))) short bf16x8;
typedef __attribute__((ext_vector_type(4))) float f32x4;

// ============ COMPILE-TIME transition tables ============
// Levels 0-3: degree-bucketed compact CSR (divergence-free level steps).
// Level 4: t-ordered, UNIFORM 5 edges/target (padded with zero-amp slot 715).
struct DevTables {
    unsigned meta[1000];       // levels 0-3 only
    unsigned edges[2860 + NST5 * 5];
    float c2[NST5];
};

constexpr DevTables build_tables() {
    DevTables T{};
    const int sizes[6] = {1, 10, 55, 220, 715, 2002};
    const int mb[5] = {0, 10, 65, 285, 1000};
    const int eb[5] = {0, 10, 110, 660, 2860};
    const float fact[6] = {1.f, 1.f, 2.f, 6.f, 24.f, 120.f};

    unsigned prev[715] = {};
    unsigned cur[2002] = {};
    int dd[2002] = {};
    int s[10] = {};
    int prevN = 1;
    prev[0] = 0u;

    for (int lvl = 1; lvl <= 5; ++lvl) {
        const int k = lvl - 1;
        const int N = sizes[lvl];
        int cnt[5] = {0, 0, 0, 0, 0};
        for (int p = 0; p < 10; ++p) s[p] = 0;
        s[0] = lvl;
        for (int t = 0; t < N; ++t) {
            unsigned P = 0;
            int d = 0;
            for (int p = 0; p < 10; ++p) {
                P |= (unsigned)s[p] << (3 * (9 - p));
                d += (s[p] > 0) ? 1 : 0;
            }
            cur[t] = P;
            dd[t] = d;
            cnt[d - 1] += 1;
            int p = 8;
            while (p >= 0 && s[p] == 0) --p;
            if (p >= 0) {
                int rest = 1;
                for (int q = p + 1; q < 10; ++q) { rest += s[q]; s[q] = 0; }
                s[p] -= 1;
                s[p + 1] = rest;
            }
        }
        int bp[5] = {}, be[5] = {};
        {
            int pp = 0, ee = 0;
            for (int d = 0; d < 5; ++d) {
                bp[d] = pp; be[d] = ee;
                pp += cnt[d]; ee += cnt[d] * (d + 1);
            }
        }
        for (int p = 0; p < 10; ++p) s[p] = 0;
        s[0] = lvl;
        for (int t = 0; t < N; ++t) {
            const int d = dd[t];
            int pos = 0, eo = 0;
            if (lvl == 5) {                 // uniform: 5 slots at t*5
                pos = -1;
                eo = t * 5;
            } else {                        // bucketed
                pos = mb[k] + bp[d - 1];
                eo = be[d - 1];
                bp[d - 1] += 1;
                be[d - 1] += d;
                T.meta[pos] = (unsigned)t | ((unsigned)d << 11) | ((unsigned)eo << 14);
            }
            int w = 0;
            for (int j = 0; j < 10; ++j) {
                if (s[j] > 0) {
                    unsigned pp2 = cur[t] - (1u << (3 * (9 - j)));
                    int lo = 0, hi = prevN - 1;
                    while (lo < hi) {
                        int mid = (lo + hi) >> 1;
                        if (prev[mid] > pp2) lo = mid + 1; else hi = mid;
                    }
                    T.edges[eb[k] + eo + w] = (unsigned)lo | ((unsigned)j << 12);
                    w += 1;
                }
            }
            if (lvl == 5) {
                for (; w < 5; ++w) T.edges[eb[k] + eo + w] = 715u;  // zero amp
                float c2 = 1.f;
                for (int j = 0; j < 10; ++j) c2 *= fact[s[j]];
                T.c2[t] = c2;
            }
            int p = 8;
            while (p >= 0 && s[p] == 0) --p;
            if (p >= 0) {
                int rest = 1;
                for (int q = p + 1; q < 10; ++q) { rest += s[q]; s[q] = 0; }
                s[p] -= 1;
                s[p + 1] = rest;
            }
        }
        if (lvl < 5) {
            for (int t = 0; t < N; ++t) prev[t] = cur[t];
            prevN = N;
        }
    }
    return T;
}

__device__ const DevTables g_T = build_tables();

// ---------- runtime scratch ----------
// A operand: PACKED u32 = bf16(hi) | bf16(lo)<<16 per element (R28/R29 best).
__device__ __align__(16) unsigned g_pack[(size_t)BATCH * KPAD];
__device__ __align__(16) unsigned short g_WhiT[64 * KPAD];   // [col][k]
__device__ __align__(16) unsigned short g_WloT[64 * KPAD];
__device__ float2 g_M[MODES][NPH];
__device__ float g_part[(size_t)KSPLIT * BATCH * 64];

__device__ __forceinline__ unsigned short f2bf(float f) {
    unsigned u = __float_as_uint(f);
    unsigned r = (u + 0x7FFF + ((u >> 16) & 1)) >> 16;   // RNE
    return (unsigned short)r;
}
__device__ __forceinline__ float bf2f(unsigned short h) {
    return __uint_as_float((unsigned)h << 16);
}

// ---------- prep: blocks 0..503 split W; block 504 builds g_M ----------
__global__ __launch_bounds__(256)
void k_prep(const float* __restrict__ theta, const float* __restrict__ W) {
    const int tid = threadIdx.x;
    if (blockIdx.x == 504) {
        __shared__ float2 Ush[MODES][NPH];
        const int r = tid / 5, c = tid % 5;
        const bool act = (tid < 50);
        float2 val = make_float2((act && r == c) ? 1.f : 0.f, 0.f);
        for (int l = 0; l < DEPTH; l++) {
            if (act && l > 0) {
                float ang = theta[(l - 1) * MODES + r];
                float s_, c_; sincosf(ang, &s_, &c_);
                float nx = val.x * c_ - val.y * s_;
                float ny = val.x * s_ + val.y * c_;
                val = make_float2(nx, ny);
            }
            if (act) Ush[r][c] = val;
            __syncthreads();
            float2 nv = val;
            if (act) {
                int o = l & 1;
                int lo = r - o;
                int partner = o + (lo ^ 1);
                if (lo >= 0 && partner < MODES) {
                    float2 pb = Ush[partner][c];
                    const float inv = 0.70710678118654752f;
                    nv.x = inv * (val.x - pb.y);
                    nv.y = inv * (val.y + pb.x);
                }
            }
            __syncthreads();
            val = nv;
        }
        if (act) g_M[r][c] = val;
        return;
    }
    int id = blockIdx.x * 256 + tid;       // 504*256 = 129024 = 64*2016
    int k = id / 64, c = id % 64;
    float w = (k < NST5) ? W[(size_t)k * 64 + c] : 0.f;
    unsigned short hi = f2bf(w);
    unsigned short lo = f2bf(w - bf2f(hi));
    g_WhiT[(size_t)c * KPAD + k] = hi;
    g_WloT[(size_t)c * KPAD + k] = lo;
}

// ---------- SLOS level step, compact edges, 4 batch elems packed ----------
__device__ __forceinline__ void slos_lvl(const float4 (*__restrict__ src)[2],
                                         float4 (*__restrict__ dst)[2],
                                         const unsigned* __restrict__ meta,
                                         const unsigned* __restrict__ edges,
                                         int N, int tid,
                                         const float4 (*Ua)[NPH],
                                         const float4 (*Ub)[NPH], int k) {
    for (int pos = tid; pos < N; pos += 256) {
        unsigned m = meta[pos];
        int t = m & 0x7FF;
        int d = (m >> 11) & 0x7;
        const unsigned* ee = edges + (m >> 14);
        float ax0 = 0.f, ay0 = 0.f, ax1 = 0.f, ay1 = 0.f;
        float ax2 = 0.f, ay2 = 0.f, ax3 = 0.f, ay3 = 0.f;
        for (int sl = 0; sl < d; sl++) {
            unsigned e = ee[sl];
            int idx = e & 0xFFF;
            int j = (e >> 12) & 0xF;
            float4 a01 = src[idx][0];
            float4 a23 = src[idx][1];
            float4 u01 = Ua[j][k];
            float4 u23 = Ub[j][k];
            ax0 = fmaf(u01.x, a01.x, ax0); ax0 = fmaf(-u01.y, a01.y, ax0);
            ay0 = fmaf(u01.x, a01.y, ay0); ay0 = fmaf( u01.y, a01.x, ay0);
            ax1 = fmaf(u01.z, a01.z, ax1); ax1 = fmaf(-u01.w, a01.w, ax1);
            ay1 = fmaf(u01.z, a01.w, ay1); ay1 = fmaf( u01.w, a01.z, ay1);
            ax2 = fmaf(u23.x, a23.x, ax2); ax2 = fmaf(-u23.y, a23.y, ax2);
            ay2 = fmaf(u23.x, a23.y, ay2); ay2 = fmaf( u23.y, a23.x, ay2);
            ax3 = fmaf(u23.z, a23.z, ax3); ax3 = fmaf(-u23.w, a23.w, ax3);
            ay3 = fmaf(u23.z, a23.w, ay3); ay3 = fmaf( u23.w, a23.z, ay3);
        }
        dst[t][0] = make_float4(ax0, ay0, ax1, ay1);
        dst[t][1] = make_float4(ax2, ay2, ax3, ay3);
    }
    __syncthreads();
}

// ---------- SLOS, 4 batch elements per block; packed u32 hi|lo out ----------
__global__ __launch_bounds__(256)
void k_slos(const float* __restrict__ x) {
    __shared__ float4 Ua[MODES][NPH];
    __shared__ float4 Ub[MODES][NPH];
    __shared__ float4 ampA[716][2];      // zero slot at 715 (level-4 padding)
    __shared__ float4 ampB[220][2];

    const int b0 = blockIdx.x * 4;
    const int tid = threadIdx.x;
    const int r = tid / 5, c = tid % 5;

    if (tid < 50) {
        const float TP = 6.28318530717958647692f;
        float s0, c0, s1, c1, s2, c2, s3, c3;
        sincosf(TP * x[(b0 + 0) * MODES + c], &s0, &c0);
        sincosf(TP * x[(b0 + 1) * MODES + c], &s1, &c1);
        sincosf(TP * x[(b0 + 2) * MODES + c], &s2, &c2);
        sincosf(TP * x[(b0 + 3) * MODES + c], &s3, &c3);
        float2 m = g_M[r][c];
        Ua[r][c] = make_float4(m.x * c0 - m.y * s0, m.x * s0 + m.y * c0,
                               m.x * c1 - m.y * s1, m.x * s1 + m.y * c1);
        Ub[r][c] = make_float4(m.x * c2 - m.y * s2, m.x * s2 + m.y * c2,
                               m.x * c3 - m.y * s3, m.x * s3 + m.y * c3);
    }
    if (tid == 0) {
        ampA[0][0] = make_float4(1.f, 0.f, 1.f, 0.f);
        ampA[0][1] = make_float4(1.f, 0.f, 1.f, 0.f);
        float4 z = make_float4(0.f, 0.f, 0.f, 0.f);
        ampA[715][0] = z; ampA[715][1] = z;   // stays zero (levels write <715)
    }
    __syncthreads();

    slos_lvl(ampA, ampB, g_T.meta + 0,   g_T.edges + 0,    10,  tid, Ua, Ub, 0);
    slos_lvl(ampB, ampA, g_T.meta + 10,  g_T.edges + 10,   55,  tid, Ua, Ub, 1);
    slos_lvl(ampA, ampB, g_T.meta + 65,  g_T.edges + 110,  220, tid, Ua, Ub, 2);
    slos_lvl(ampB, ampA, g_T.meta + 285, g_T.edges + 660,  715, tid, Ua, Ub, 3);

    // level 4: uniform 5 edges/target, t-ordered, branchless unrolled
    unsigned* po0 = g_pack + (size_t)b0 * KPAD;
    unsigned* po1 = po0 + KPAD;
    unsigned* po2 = po1 + KPAD;
    unsigned* po3 = po2 + KPAD;
    const unsigned* edges = g_T.edges + 2860;
    for (int t = tid; t < NST5; t += 256) {
        const unsigned* ee = edges + t * 5;
        float ax0 = 0.f, ay0 = 0.f, ax1 = 0.f, ay1 = 0.f;
        float ax2 = 0.f, ay2 = 0.f, ax3 = 0.f, ay3 = 0.f;
        #pragma unroll
        for (int sl = 0; sl < 5; sl++) {
            unsigned e = ee[sl];
            int idx = e & 0xFFF;
            int j = (e >> 12) & 0xF;
            float4 a01 = ampA[idx][0];
            float4 a23 = ampA[idx][1];
            float4 u01 = Ua[j][4];
            float4 u23 = Ub[j][4];
            ax0 = fmaf(u01.x, a01.x, ax0); ax0 = fmaf(-u01.y, a01.y, ax0);
            ay0 = fmaf(u01.x, a01.y, ay0); ay0 = fmaf( u01.y, a01.x, ay0);
            ax1 = fmaf(u01.z, a01.z, ax1); ax1 = fmaf(-u01.w, a01.w, ax1);
            ay1 = fmaf(u01.z, a01.w, ay1); ay1 = fmaf( u01.w, a01.z, ay1);
            ax2 = fmaf(u23.x, a23.x, ax2); ax2 = fmaf(-u23.y, a23.y, ax2);
            ay2 = fmaf(u23.x, a23.y, ay2); ay2 = fmaf( u23.y, a23.x, ay2);
            ax3 = fmaf(u23.z, a23.z, ax3); ax3 = fmaf(-u23.w, a23.w, ax3);
            ay3 = fmaf(u23.z, a23.w, ay3); ay3 = fmaf( u23.w, a23.z, ay3);
        }
        float c2v = g_T.c2[t];
        float v[4] = {c2v * (ax0 * ax0 + ay0 * ay0),
                      c2v * (ax1 * ax1 + ay1 * ay1),
                      c2v * (ax2 * ax2 + ay2 * ay2),
                      c2v * (ax3 * ax3 + ay3 * ay3)};
        unsigned pk[4];
        #pragma unroll
        for (int q = 0; q < 4; q++) {
            unsigned short hi = f2bf(v[q]);
            unsigned short lo = f2bf(v[q] - bf2f(hi));
            pk[q] = (unsigned)hi | ((unsigned)lo << 16);
        }
        po0[t] = pk[0];
        po1[t] = pk[1];
        po2[t] = pk[2];
        po3[t] = pk[3];
    }
    for (int t = NST5 + tid; t < KPAD; t += 256) {
        po0[t] = 0u; po1[t] = 0u; po2[t] = 0u; po3[t] = 0u;
    }
}

// ---------- MFMA GEMM: g_part[kc] = P x W, packed-u32 A, B staged in LDS ----
// (R32: measured best, gemm ~7.5us.) grid (64,16), 4 waves; block's B-chunk
// (32KB hi+lo) staged once via coalesced 16B reads; inner loop = 2 global A
// loads + 8 LDS reads + 12 MFMAs per 32-k step.
__global__ __launch_bounds__(256)
void k_gemm_mfma() {
    __shared__ unsigned short Bh[64][136];   // [col][k-ks], +8 u16 pad
    __shared__ unsigned short Bl[64][136];

    const int bm = blockIdx.x;
    const int kc = blockIdx.y;
    const int wv = threadIdx.x >> 6;
    const int ln = threadIdx.x & 63;
    const int lc = ln & 15;
    const int kg = (ln >> 4) * 8;
    const int row = bm * 64 + wv * 16 + lc;
    const int ks = kc * 128;
    const int ke = (ks + 128 < KPAD) ? ks + 128 : KPAD;   // kc=15 -> 96 wide
    const int kw = ke - ks;                                // 128 or 96

    {
        const int nch = kw / 8;              // 16B chunks per col (16 or 12)
        const int total = 64 * nch;          // 1024 or 768
        for (int cch = threadIdx.x; cch < total; cch += 256) {
            int col = cch / nch;
            int k8 = (cch % nch) * 8;
            *(uint4*)&Bh[col][k8] =
                *(const uint4*)(g_WhiT + (size_t)col * KPAD + ks + k8);
            *(uint4*)&Bl[col][k8] =
                *(const uint4*)(g_WloT + (size_t)col * KPAD + ks + k8);
        }
    }
    __syncthreads();

    f32x4 acc[4] = {f32x4{0.f, 0.f, 0.f, 0.f}, f32x4{0.f, 0.f, 0.f, 0.f},
                    f32x4{0.f, 0.f, 0.f, 0.f}, f32x4{0.f, 0.f, 0.f, 0.f}};
    const unsigned* pA = g_pack + (size_t)row * KPAD;

    for (int k0 = ks; k0 < ke; k0 += 32) {
        uint4 w0 = *(const uint4*)(pA + k0 + kg);
        uint4 w1 = *(const uint4*)(pA + k0 + kg + 4);
        unsigned pw[8] = {w0.x, w0.y, w0.z, w0.w, w1.x, w1.y, w1.z, w1.w};
        bf16x8 ahi, alo;
        #pragma unroll
        for (int i = 0; i < 8; i++) {
            ahi[i] = (short)(pw[i] & 0xFFFFu);
            alo[i] = (short)(pw[i] >> 16);
        }
        const int koff = k0 - ks + kg;
        #pragma unroll
        for (int n = 0; n < 4; n++) {
            bf16x8 bhi = *(const bf16x8*)&Bh[n * 16 + lc][koff];
            bf16x8 blo = *(const bf16x8*)&Bl[n * 16 + lc][koff];
            acc[n] = __builtin_amdgcn_mfma_f32_16x16x32_bf16(ahi, bhi, acc[n], 0, 0, 0);
            acc[n] = __builtin_amdgcn_mfma_f32_16x16x32_bf16(ahi, blo, acc[n], 0, 0, 0);
            acc[n] = __builtin_amdgcn_mfma_f32_16x16x32_bf16(alo, bhi, acc[n], 0, 0, 0);
        }
    }

    float* po = g_part + ((size_t)kc * BATCH + bm * 64 + wv * 16) * 64;
    #pragma unroll
    for (int n = 0; n < 4; n++)
        #pragma unroll
        for (int i = 0; i < 4; i++)
            po[(size_t)((ln >> 4) * 4 + i) * 64 + n * 16 + lc] = acc[n][i];
}

// ---------- reduce KSPLIT partials + bias (float4-vectorized) ----------
// Each thread owns 4 consecutive outputs: 16 dwordx4 loads + 1 dwordx4 store
// (was 16 scalar loads + 1 scalar store per output).
__global__ __launch_bounds__(256)
void k_reduce(const float* __restrict__ bias, float* __restrict__ out) {
    int i4 = blockIdx.x * 256 + threadIdx.x;     // 256 blocks x 256 = 65536
    const int TOT = BATCH * 64;
    int i = i4 * 4;
    if (i < TOT) {
        float4 v = *(const float4*)&bias[i & 63]; // i%64 is multiple of 4
        #pragma unroll
        for (int m = 0; m < KSPLIT; m++) {
            float4 p = *(const float4*)&g_part[(size_t)m * TOT + i];
            v.x += p.x; v.y += p.y; v.z += p.z; v.w += p.w;
        }
        *(float4*)&out[i] = v;
    }
}

extern "C" void kernel_launch(void* const* d_in, const int* in_sizes, int n_in,
                              void* d_out, int out_size, void* d_ws, size_t ws_size,
                              hipStream_t stream) {
    const float* x     = (const float*)d_in[0];
    const float* theta = (const float*)d_in[1];
    const float* W     = (const float*)d_in[2];
    const float* bias  = (const float*)d_in[3];
    float* out = (float*)d_out;
    (void)d_ws; (void)ws_size; (void)in_sizes; (void)n_in; (void)out_size;

    k_prep<<<505, 256, 0, stream>>>(theta, W);
    k_slos<<<BATCH / 4, 256, 0, stream>>>(x);
    k_gemm_mfma<<<dim3(64, KSPLIT), 256, 0, stream>>>();
    k_reduce<<<256, 256, 0, stream>>>(bias, out);
}